// Round 1
// baseline (612.751 us; speedup 1.0000x reference)
//
#include <hip/hip_runtime.h>
#include <stdint.h>

// Problem constants (reference: N=8192, IN_DIM=512, LDIM=256)
#define NN 8192
#define KDIM 512
#define LDIM 256

typedef short bf16x8 __attribute__((ext_vector_type(8)));
typedef short short8 __attribute__((ext_vector_type(8)));
typedef float f32x4 __attribute__((ext_vector_type(4)));
typedef unsigned short u16x4 __attribute__((ext_vector_type(4)));

// fp32 -> bf16 with round-to-nearest-even
__device__ __forceinline__ unsigned short f2bf(float f) {
  unsigned int u = __float_as_uint(f);
  u = (u + 0x7fffu + ((u >> 16) & 1u)) >> 16;
  return (unsigned short)u;
}
__device__ __forceinline__ float bf2f(unsigned short s) {
  return __uint_as_float(((unsigned int)s) << 16);
}

// async global->LDS, 16B per lane; LDS dest = wave-uniform base + lane*16
__device__ __forceinline__ void async_ld16(const unsigned short* g, void* l) {
  __builtin_amdgcn_global_load_lds(
      (const __attribute__((address_space(1))) unsigned int*)g,
      (__attribute__((address_space(3))) unsigned int*)l, 16, 0, 0);
}

// Cast x [8192x512] and proj_w [256x512] to bf16. 4 floats/thread (float4 in,
// u16x4 out). Grid exactly covers x/4.
__global__ __launch_bounds__(256) void cast_kernel(
    const float* __restrict__ x, const float* __restrict__ pw,
    unsigned short* __restrict__ xb, unsigned short* __restrict__ pwb) {
  const int i = blockIdx.x * 256 + threadIdx.x;  // float4 index
  float4 v = ((const float4*)x)[i];
  u16x4 o;
  o[0] = (short)f2bf(v.x); o[1] = (short)f2bf(v.y);
  o[2] = (short)f2bf(v.z); o[3] = (short)f2bf(v.w);
  ((u16x4*)xb)[i] = o;
  if (i < (LDIM * KDIM) / 4) {
    float4 w = ((const float4*)pw)[i];
    u16x4 ow;
    ow[0] = (short)f2bf(w.x); ow[1] = (short)f2bf(w.y);
    ow[2] = (short)f2bf(w.z); ow[3] = (short)f2bf(w.w);
    ((u16x4*)pwb)[i] = ow;
  }
}

// Row-normalize x_hat, emit A = bf16(xn*w), B = bf16(xn). One block per row.
__global__ __launch_bounds__(256) void norm_kernel(
    const float* __restrict__ xh, const float* __restrict__ w,
    unsigned short* __restrict__ Ab, unsigned short* __restrict__ Bb) {
  const int row = blockIdx.x;
  const int d = threadIdx.x;
  const float v = xh[row * LDIM + d];
  float ss = v * v;
#pragma unroll
  for (int m = 1; m < 64; m <<= 1) ss += __shfl_xor(ss, m);
  __shared__ float s4[4];
  if ((d & 63) == 0) s4[d >> 6] = ss;
  __syncthreads();
  const float tot = s4[0] + s4[1] + s4[2] + s4[3];
  const float inv = 1.0f / sqrtf(tot);
  const float xn = v * inv;
  Bb[row * LDIM + d] = f2bf(xn);
  Ab[row * LDIM + d] = f2bf(xn * w[d]);
}

// D = A * B^T, A [M,K] bf16 K-major, B [N,K] bf16 K-major.
// 128x128 tile, BK=32, 256 threads = 4 waves (2x2), each wave 64x64 via
// 4x4 grid of v_mfma_f32_16x16x32_bf16.
// Main loop: minimum 2-phase double-buffer (T3 recipe): stage next K-step
// BEFORE current ds_read+MFMA; ONE __syncthreads per K-step (its implicit
// vmcnt(0)+lgkmcnt(0) drain IS the recipe's "vmcnt(0); barrier").
// MODE 0: store D (fp32) to C (ldC cols).                      [GEMM1]
// MODE 1: t = adj*exp(-D) -> bf16 to T; rowsum atomics.        [GEMM2, big ws]
// MODE 2: t = adj*exp(-D) -> fp32 to C; rowsum atomics.        [GEMM2, fallback]
// MODE 1/2 epilogue: ONE full-tile 128x132 LDS transpose (repurposes the
// staging LDS, dead after the K-loop) -> 2 barriers instead of 8, then a
// barrier-free adj/exp/pack phase: each thread owns a 64-col half-row
// (16 float4 adj loads in flight, contiguous 128B T stores).
template <int K, int MODE>
__global__ __launch_bounds__(256) void gemm_bt(
    const unsigned short* __restrict__ A,
    const unsigned short* __restrict__ B,
    float* __restrict__ C,
    unsigned short* __restrict__ T,
    const float* __restrict__ adj,
    float* __restrict__ rowsum,
    int ldC) {
  // MODE 0: 2x(As+Bs) = 32 KB. MODE 1/2: max(32 KB staging, 128*132*4 trans).
  constexpr int SMEM_BYTES = (MODE == 0) ? 32768 : 128 * 132 * 4;  // 67584
  __shared__ alignas(16) char sm[SMEM_BYTES];
  __shared__ float rs[128];

  const int tid = threadIdx.x;
  const int wave = tid >> 6;
  const int lane = tid & 63;
  const int quad = lane >> 4;
  const int l16 = lane & 15;
  const int wm = wave >> 1;
  const int wn = wave & 1;

  const size_t row0 = (size_t)blockIdx.y * 128;
  const size_t col0 = (size_t)blockIdx.x * 128;

  // staging map: chunk c = wave*128 + lane covers LDS bytes [c*16, c*16+16)
  // within a buffer; tile layout [128 rows][32 k] bf16 => row m = c>>2,
  // k offset = (c&3)*8. Wave w stages rows w*32..w*32+31.
  const int c0 = wave * 128 + lane;
  const int mA = c0 >> 2;
  const int kA = (c0 & 3) * 8;
  const unsigned short* Ag = A + (row0 + mA) * (size_t)K + kA;
  const unsigned short* Bg = B + (col0 + mA) * (size_t)K + kA;

  // double-buffer: buf0 A at sm+0, B at sm+8192; buf1 A at +16384, B at +24576
  char* const a0d = sm + wave * 2048;
  char* const b0d = sm + 8192 + wave * 2048;
  char* const a1d = sm + 16384 + wave * 2048;
  char* const b1d = sm + 24576 + wave * 2048;

  f32x4 acc[4][4];
#pragma unroll
  for (int i = 0; i < 4; ++i)
#pragma unroll
    for (int j = 0; j < 4; ++j) acc[i][j] = (f32x4)(0.0f);

  auto stage = [&](char* Ad, char* Bd, int k0) {
    async_ld16(Ag + k0, Ad);
    async_ld16(Ag + 16 * (size_t)K + k0, Ad + 1024);  // row m+16, same k offset
    async_ld16(Bg + k0, Bd);
    async_ld16(Bg + 16 * (size_t)K + k0, Bd + 1024);
  };
  auto compute = [&](const char* Ab_, const char* Bb_) {
    bf16x8 av[4], bv[4];
#pragma unroll
    for (int mt = 0; mt < 4; ++mt)
      av[mt] = *(const bf16x8*)(Ab_ + (wm * 64 + mt * 16 + l16) * 64 + quad * 16);
#pragma unroll
    for (int nt = 0; nt < 4; ++nt)
      bv[nt] = *(const bf16x8*)(Bb_ + (wn * 64 + nt * 16 + l16) * 64 + quad * 16);
#pragma unroll
    for (int mt = 0; mt < 4; ++mt)
#pragma unroll
      for (int nt = 0; nt < 4; ++nt)
        acc[mt][nt] = __builtin_amdgcn_mfma_f32_16x16x32_bf16(
            av[mt], bv[nt], acc[mt][nt], 0, 0, 0);
  };

  // prologue
  stage(a0d, b0d, 0);
  __syncthreads();
  // steady state: 2 K-steps per trip, one barrier per K-step
  for (int k0 = 0; k0 < K; k0 += 64) {
    if (k0 + 32 < K) stage(a1d, b1d, k0 + 32);   // prefetch overlaps compute
    compute(sm, sm + 8192);
    __syncthreads();
    if (k0 + 64 < K) stage(a0d, b0d, k0 + 64);
    if (k0 + 32 < K) compute(sm + 16384, sm + 24576);
    __syncthreads();
  }

  if constexpr (MODE == 0) {
#pragma unroll
    for (int mt = 0; mt < 4; ++mt)
#pragma unroll
      for (int nt = 0; nt < 4; ++nt)
#pragma unroll
        for (int r = 0; r < 4; ++r) {
          // C/D layout: col = lane&15, row = quad*4 + reg [m89/m91 verified]
          size_t gr = row0 + wm * 64 + mt * 16 + quad * 4 + r;
          size_t gc = col0 + wn * 64 + nt * 16 + l16;
          C[gr * (size_t)ldC + gc] = acc[mt][nt][r];
        }
  } else {
    // Full-tile transpose into repurposed LDS. Stride 132 floats:
    // scatter (fixed quad-row pattern) is 2-way bank (free);
    // gather float4 reads are 4-way (1.58x) -- acceptable.
    float* trans = (float*)sm;
#pragma unroll
    for (int mt = 0; mt < 4; ++mt)
#pragma unroll
      for (int nt = 0; nt < 4; ++nt)
#pragma unroll
        for (int r = 0; r < 4; ++r)
          trans[(wm * 64 + mt * 16 + quad * 4 + r) * 132 +
                wn * 64 + nt * 16 + l16] = acc[mt][nt][r];
    __syncthreads();

    // gather: thread -> (row r16, half h); 64 contiguous cols each.
    const int r16 = tid >> 1;  // 0..127 tile row
    const int h = tid & 1;     // 0/1: cols [h*64, h*64+64)
    const size_t gr = row0 + r16;
    const float4* arow = (const float4*)(adj + gr * NN + col0 + h * 64);
    const float4* drow = (const float4*)(trans + r16 * 132 + h * 64);
    f32x4 ps = (f32x4)(0.0f);  // 4-lane partial rowsum for ILP
#pragma unroll
    for (int g = 0; g < 4; ++g) {
      float4 a4[4], d4[4];
#pragma unroll
      for (int q = 0; q < 4; ++q) {
        a4[q] = arow[g * 4 + q];
        d4[q] = drow[g * 4 + q];
      }
      float tv[16];
#pragma unroll
      for (int q = 0; q < 4; ++q) {
        tv[q * 4 + 0] = a4[q].x * __expf(-d4[q].x);
        tv[q * 4 + 1] = a4[q].y * __expf(-d4[q].y);
        tv[q * 4 + 2] = a4[q].z * __expf(-d4[q].z);
        tv[q * 4 + 3] = a4[q].w * __expf(-d4[q].w);
      }
      if constexpr (MODE == 1) {
        short8 p0, p1;
#pragma unroll
        for (int j = 0; j < 16; ++j) {
          unsigned short us = f2bf(tv[j]);
          ps[j & 3] += bf2f(us);  // rowsum of the *rounded* t: self-consistent
          if (j < 8) p0[j] = (short)us; else p1[j - 8] = (short)us;
        }
        short8* trow = (short8*)(T + gr * NN + col0 + h * 64 + g * 16);
        trow[0] = p0;
        trow[1] = p1;
      } else {
        float4 o[4];
#pragma unroll
        for (int j = 0; j < 16; ++j) {
          ps[j & 3] += tv[j];
          ((float*)o)[j] = tv[j];
        }
        float4* crow = (float4*)(C + gr * NN + col0 + h * 64 + g * 16);
#pragma unroll
        for (int q = 0; q < 4; ++q) crow[q] = o[q];
      }
    }
    float part = ps[0] + ps[1] + ps[2] + ps[3];
    part += __shfl_xor(part, 1);  // combine the two halves of row r16
    if (h == 0) rs[r16] = part;   // unique owner per tile row
    __syncthreads();
    if (tid < 128) atomicAdd(&rowsum[row0 + tid], rs[tid]);
  }
}

// out = bf16(t) * (1/rowsum[row]) + 1e-10; 16 elems/thread:
// read 2x short8 (32B), write 4x float4 (64B)
__global__ __launch_bounds__(256) void scale_bf16_kernel(
    const unsigned short* __restrict__ T, const float* __restrict__ rowsum,
    float* __restrict__ out) {
  const size_t i = (size_t)blockIdx.x * 256 + threadIdx.x;  // 16-elem chunk
  const int row = (int)(i >> 9);  // 512 chunks per row
  const float inv = 1.0f / rowsum[row];
  short8 t0 = ((const short8*)T)[i * 2];
  short8 t1 = ((const short8*)T)[i * 2 + 1];
  float4 o0, o1, o2, o3;
  o0.x = bf2f((unsigned short)t0[0]) * inv + 1e-10f;
  o0.y = bf2f((unsigned short)t0[1]) * inv + 1e-10f;
  o0.z = bf2f((unsigned short)t0[2]) * inv + 1e-10f;
  o0.w = bf2f((unsigned short)t0[3]) * inv + 1e-10f;
  o1.x = bf2f((unsigned short)t0[4]) * inv + 1e-10f;
  o1.y = bf2f((unsigned short)t0[5]) * inv + 1e-10f;
  o1.z = bf2f((unsigned short)t0[6]) * inv + 1e-10f;
  o1.w = bf2f((unsigned short)t0[7]) * inv + 1e-10f;
  o2.x = bf2f((unsigned short)t1[0]) * inv + 1e-10f;
  o2.y = bf2f((unsigned short)t1[1]) * inv + 1e-10f;
  o2.z = bf2f((unsigned short)t1[2]) * inv + 1e-10f;
  o2.w = bf2f((unsigned short)t1[3]) * inv + 1e-10f;
  o3.x = bf2f((unsigned short)t1[4]) * inv + 1e-10f;
  o3.y = bf2f((unsigned short)t1[5]) * inv + 1e-10f;
  o3.z = bf2f((unsigned short)t1[6]) * inv + 1e-10f;
  o3.w = bf2f((unsigned short)t1[7]) * inv + 1e-10f;
  float4* dst = (float4*)(out + i * 16);
  dst[0] = o0; dst[1] = o1; dst[2] = o2; dst[3] = o3;
}

// Fallback: in-place out = t / rowsum[row] + 1e-10 (t fp32 already in out)
__global__ __launch_bounds__(256) void scale_f32_kernel(
    float* __restrict__ t, const float* __restrict__ rowsum) {
  const size_t i = (size_t)blockIdx.x * 256 + threadIdx.x;
  const int row = (int)(i >> 11);
  float4 v = ((float4*)t)[i];
  const float inv = 1.0f / rowsum[row];
  v.x = v.x * inv + 1e-10f;
  v.y = v.y * inv + 1e-10f;
  v.z = v.z * inv + 1e-10f;
  v.w = v.w * inv + 1e-10f;
  ((float4*)t)[i] = v;
}

extern "C" void kernel_launch(void* const* d_in, const int* in_sizes, int n_in,
                              void* d_out, int out_size, void* d_ws, size_t ws_size,
                              hipStream_t stream) {
  (void)in_sizes; (void)n_in; (void)out_size;
  const float* x   = (const float*)d_in[0];  // [8192,512]
  const float* adj = (const float*)d_in[1];  // [8192,8192]
  const float* pw  = (const float*)d_in[2];  // [256,512]
  const float* lw  = (const float*)d_in[3];  // [256]
  float* out = (float*)d_out;                // [8192,8192]
  char* ws = (char*)d_ws;

  // ws layout (bytes)
  unsigned short* xb   = (unsigned short*)(ws);              // 8 MB
  unsigned short* pwb  = (unsigned short*)(ws + 8388608);    // 256 KB
  float*          xhat = (float*)(ws + 8650752);             // 8 MB
  unsigned short* Ab   = (unsigned short*)(ws + 17039360);   // 4 MB
  unsigned short* Bb   = (unsigned short*)(ws + 21233664);   // 4 MB
  float*          rsum = (float*)(ws + 25427968);            // 32 KB
  unsigned short* Tbuf = (unsigned short*)(ws + 25460736);   // 128 MB (if fits)
  const bool big_ws = ws_size >= 25460736ull + (size_t)NN * NN * 2ull;

  // 1) cast inputs to bf16 (4 floats/thread)
  cast_kernel<<<(NN * KDIM) / (256 * 4), 256, 0, stream>>>(x, pw, xb, pwb);
  // 2) x_hat = x @ proj_w^T : M=8192, N=256, K=512
  gemm_bt<KDIM, 0><<<dim3(2, 64), 256, 0, stream>>>(xb, pwb, xhat, nullptr, nullptr, nullptr, LDIM);
  // 3) normalize rows; A = xn*w, B = xn (bf16)
  norm_kernel<<<NN, 256, 0, stream>>>(xhat, lw, Ab, Bb);
  // 4) t = adj * exp(-(A@B^T)), plus rowsums
  hipMemsetAsync(rsum, 0, NN * sizeof(float), stream);
  if (big_ws) {
    gemm_bt<LDIM, 1><<<dim3(64, 64), 256, 0, stream>>>(Ab, Bb, nullptr, Tbuf, adj, rsum, NN);
    // 5) out = t / rowsum + eps (16 elems/thread)
    scale_bf16_kernel<<<(NN * NN) / (16 * 256), 256, 0, stream>>>(Tbuf, rsum, out);
  } else {
    gemm_bt<LDIM, 2><<<dim3(64, 64), 256, 0, stream>>>(Ab, Bb, out, nullptr, adj, rsum, NN);
    scale_f32_kernel<<<(NN / 4) * (NN / 256), 256, 0, stream>>>(out, rsum);
  }
}